// Round 2
// baseline (1840.745 us; speedup 1.0000x reference)
//
#include <hip/hip_runtime.h>
#include <hip/hip_bf16.h>

#define V_ 50000
#define E_ 100
#define H_ 128
#define B_ 16
#define S_ 4096

typedef unsigned short u16;
typedef unsigned int   u32;

__device__ __forceinline__ float bf2f(u16 x) {
  return __uint_as_float(((u32)x) << 16);
}
__device__ __forceinline__ float sigm(float x) { return 1.0f / (1.0f + __expf(-x)); }
__device__ __forceinline__ float tanh_f(float x) {
  float e = __expf(2.0f * x);
  return 1.0f - 2.0f / (e + 1.0f);
}

// ---------------------------------------------------------------------------
// Transpose W_x (f32, [512][100] row-major; o = g*128+h) into k-major
// interleaved layout: Wt[(k/4)*512*4 + o*4 + (k%4)] (f32) so the xg kernel
// does one coalesced float4 load per 4-k chunk per output.
// ---------------------------------------------------------------------------
__global__ void prep_wt(const float* __restrict__ Wx, float* __restrict__ Wt) {
  int i = blockIdx.x * 256 + threadIdx.x;        // over 512*100
  if (i < 512 * E_) {
    int o = i / E_, k = i % E_;
    Wt[((size_t)(k >> 2) * 512 + o) * 4 + (k & 3)] = Wx[i];
  }
}

// ---------------------------------------------------------------------------
// xg[row][o] = dot(emb[seq[row]], W_x[o]) + b_x[o], row in [0, B*S), o in [0,512)
// 512 threads (1 out each), 32 rows per block. Embedding values are
// block-uniform -> scalar (s_load) fetches; W via coalesced float4.
// xg is stored as bf16 (halves traffic + workspace; error << threshold).
// ---------------------------------------------------------------------------
#define XGR 32
__global__ __launch_bounds__(512) void xg_kernel(
    const float* __restrict__ emb, const float* __restrict__ Wt,
    const float* __restrict__ bx, const int* __restrict__ seq,
    u16* __restrict__ xg)
{
  const int o = threadIdx.x;
  const int row0 = blockIdx.x * XGR;

  int tb[XGR];
  #pragma unroll
  for (int r = 0; r < XGR; ++r)
    tb[r] = __builtin_amdgcn_readfirstlane(seq[row0 + r]) * E_;

  float acc[XGR];
  #pragma unroll
  for (int r = 0; r < XGR; ++r) acc[r] = 0.0f;

  for (int k0 = 0; k0 < E_; k0 += 4) {
    float4 wv = *reinterpret_cast<const float4*>(Wt + ((size_t)(k0 >> 2) * 512 + o) * 4);
    #pragma unroll
    for (int r = 0; r < XGR; ++r) {
      float e0 = emb[tb[r] + k0];
      float e1 = emb[tb[r] + k0 + 1];
      float e2 = emb[tb[r] + k0 + 2];
      float e3 = emb[tb[r] + k0 + 3];
      acc[r] += e0 * wv.x + e1 * wv.y + e2 * wv.z + e3 * wv.w;
    }
  }
  float bxv = bx[o];
  #pragma unroll
  for (int r = 0; r < XGR; ++r) {
    ((__hip_bfloat16*)xg)[(size_t)(row0 + r) * 512 + o] = __float2bfloat16(acc[r] + bxv);
  }
}

// ---------------------------------------------------------------------------
// Level 0: h_l=h_r=c_l=c_r=0 -> c = sig(i)*tanh(u), h = sig(o)*tanh(c).
// Only gates i(xg0), o(xg2), u(xg3) matter (f gates multiply zero c).
// ---------------------------------------------------------------------------
__global__ __launch_bounds__(256) void level0_kernel(
    const u16* __restrict__ xg, const float* __restrict__ bl, const float* __restrict__ br,
    float* __restrict__ h0, float* __restrict__ c0)
{
  int t = blockIdx.x * 256 + threadIdx.x;        // over B*S*H
  int hh = t & (H_ - 1);
  size_t row = (size_t)(t >> 7);
  const u16* xr = xg + row * 512;
  float pi = bf2f(xr[hh])          + bl[hh]          + br[hh];
  float po = bf2f(xr[2 * H_ + hh]) + bl[3 * H_ + hh] + br[3 * H_ + hh];
  float pu = bf2f(xr[3 * H_ + hh]) + bl[4 * H_ + hh] + br[4 * H_ + hh];
  float c = sigm(pi) * tanh_f(pu);
  float h = sigm(po) * tanh_f(c);
  h0[t] = h;
  c0[t] = c;
}

// ---------------------------------------------------------------------------
// Levels 1..12. Block = 128 threads (one per h), ND nodes per block.
// pre[g][h] = xg[b,dep[j],XMAP[g],h] + b_l[g,h] + b_r[g,h]
//           + dot(U_l[g,h,:], h_l) + dot(U_r[g,h,:], h_r)
// U rows: per-lane unique float4 global loads, reused over ND nodes.
// h_l/h_r: block-uniform addresses -> compiler emits s_load; v_fmac v,s,v.
// ---------------------------------------------------------------------------
template<int ND>
__global__ __launch_bounds__(128) void level_kernel(
    const u16* __restrict__ xg,
    const float* __restrict__ Ul, const float* __restrict__ bl,
    const float* __restrict__ Ur, const float* __restrict__ br,
    const int* __restrict__ deprow,
    const float* __restrict__ hPrev, const float* __restrict__ cPrev,
    float* __restrict__ hOut, float* __restrict__ cOut, int n)
{
  const int hh = threadIdx.x;
  const int b  = blockIdx.y;
  const int j0 = blockIdx.x * ND;

  float blv[5], brv[5];
  #pragma unroll
  for (int g = 0; g < 5; ++g) {
    blv[g] = bl[g * H_ + hh];
    brv[g] = br[g * H_ + hh];
  }

  float acc[ND][5];
  #pragma unroll
  for (int u = 0; u < ND; ++u) {
    int dj = __builtin_amdgcn_readfirstlane(deprow[j0 + u]);
    const u16* xr = xg + ((size_t)b * S_ + dj) * 512;
    float x0 = bf2f(xr[hh]);
    float x1 = bf2f(xr[H_ + hh]);
    float x2 = bf2f(xr[2 * H_ + hh]);
    float x3 = bf2f(xr[3 * H_ + hh]);
    acc[u][0] = x0 + blv[0] + brv[0];   // i   <- xg gate 0
    acc[u][1] = x1 + blv[1] + brv[1];   // f_l <- xg gate 1
    acc[u][2] = x1 + blv[2] + brv[2];   // f_r <- xg gate 1
    acc[u][3] = x2 + blv[3] + brv[3];   // o   <- xg gate 2
    acc[u][4] = x3 + blv[4] + brv[4];   // u   <- xg gate 3
  }

  const float* hb = hPrev + ((size_t)b * 2 * n + 2 * j0) * H_;
  const float* ulp = Ul + (size_t)hh * H_;
  const float* urp = Ur + (size_t)hh * H_;

  for (int k0 = 0; k0 < H_; k0 += 4) {
    float ul[5][4], ur[5][4];
    #pragma unroll
    for (int g = 0; g < 5; ++g) {
      float4 a  = *reinterpret_cast<const float4*>(ulp + (size_t)g * H_ * H_ + k0);
      float4 c4 = *reinterpret_cast<const float4*>(urp + (size_t)g * H_ * H_ + k0);
      ul[g][0] = a.x;  ul[g][1] = a.y;  ul[g][2] = a.z;  ul[g][3] = a.w;
      ur[g][0] = c4.x; ur[g][1] = c4.y; ur[g][2] = c4.z; ur[g][3] = c4.w;
    }
    #pragma unroll
    for (int u = 0; u < ND; ++u) {
      #pragma unroll
      for (int j = 0; j < 4; ++j) {
        float hl = hb[(size_t)(2 * u) * H_ + k0 + j];       // uniform -> s_load
        float hr = hb[(size_t)(2 * u + 1) * H_ + k0 + j];   // uniform -> s_load
        #pragma unroll
        for (int g = 0; g < 5; ++g) {
          acc[u][g] += ul[g][j] * hl;
          acc[u][g] += ur[g][j] * hr;
        }
      }
    }
  }

  #pragma unroll
  for (int u = 0; u < ND; ++u) {
    float iv = sigm(acc[u][0]);
    float fl = sigm(acc[u][1]);
    float fr = sigm(acc[u][2]);
    float ov = sigm(acc[u][3]);
    float uv = tanh_f(acc[u][4]);
    size_t pidx = ((size_t)b * 2 * n + 2 * (j0 + u)) * H_ + hh;
    float cl = cPrev[pidx];
    float cr = cPrev[pidx + H_];
    float c = iv * uv + fl * cl + fr * cr;
    float h = ov * tanh_f(c);
    size_t oidx = ((size_t)b * n + (j0 + u)) * H_ + hh;
    hOut[oidx] = h;
    cOut[oidx] = c;
  }
}

// ---------------------------------------------------------------------------
// Final: out = concat(h[:,0].flatten(), c[:,0].flatten()) as f32 (2048 + 2048)
// ---------------------------------------------------------------------------
__global__ void out_kernel(const float* __restrict__ hF, const float* __restrict__ cF,
                           float* __restrict__ out) {
  int i = blockIdx.x * 256 + threadIdx.x;
  if (i < B_ * H_)            out[i] = hF[i];
  else if (i < 2 * B_ * H_)   out[i] = cF[i - B_ * H_];
}

extern "C" void kernel_launch(void* const* d_in, const int* in_sizes, int n_in,
                              void* d_out, int out_size, void* d_ws, size_t ws_size,
                              hipStream_t stream)
{
  const float* emb = (const float*)d_in[0];
  const float* Wx  = (const float*)d_in[1];
  const float* bx  = (const float*)d_in[2];
  const float* Ul  = (const float*)d_in[3];
  const float* bl  = (const float*)d_in[4];
  const float* Ur  = (const float*)d_in[5];
  const float* br  = (const float*)d_in[6];
  const int* seq = (const int*)d_in[7];
  const int* dep = (const int*)d_in[8];

  char* p = (char*)d_ws;
  float* Wt = (float*)p;  p += (size_t)512 * E_ * 4;            // 204800
  u16* xg = (u16*)p;      p += (size_t)B_ * S_ * 512 * 2;       // 67,108,864 (bf16)
  float* hA = (float*)p;  p += (size_t)B_ * S_ * H_ * 4;        // 33,554,432
  float* cA = (float*)p;  p += (size_t)B_ * S_ * H_ * 4;
  float* hB = (float*)p;  p += (size_t)B_ * (S_ / 2) * H_ * 4;  // 16,777,216
  float* cB = (float*)p;  p += (size_t)B_ * (S_ / 2) * H_ * 4;

  prep_wt<<<dim3((512 * E_ + 255) / 256), dim3(256), 0, stream>>>(Wx, Wt);
  xg_kernel<<<dim3(B_ * S_ / XGR), dim3(512), 0, stream>>>(emb, Wt, bx, seq, xg);
  level0_kernel<<<dim3(B_ * S_ * H_ / 256), dim3(256), 0, stream>>>(xg, bl, br, hA, cA);

  float *hp = hA, *cp = cA, *ho = hB, *co = cB;
  for (int l = 1; l < 13; ++l) {
    int n = S_ >> l;
    const int* deprow = dep + (size_t)(l - 1) * (S_ / 2);
    int nd = n < 8 ? n : 8;
    dim3 grid(n / nd, B_);
    switch (nd) {
      case 8: level_kernel<8><<<grid, 128, 0, stream>>>(xg, Ul, bl, Ur, br, deprow, hp, cp, ho, co, n); break;
      case 4: level_kernel<4><<<grid, 128, 0, stream>>>(xg, Ul, bl, Ur, br, deprow, hp, cp, ho, co, n); break;
      case 2: level_kernel<2><<<grid, 128, 0, stream>>>(xg, Ul, bl, Ur, br, deprow, hp, cp, ho, co, n); break;
      case 1: level_kernel<1><<<grid, 128, 0, stream>>>(xg, Ul, bl, Ur, br, deprow, hp, cp, ho, co, n); break;
    }
    float* t;
    t = hp; hp = ho; ho = t;
    t = cp; cp = co; co = t;
  }

  out_kernel<<<dim3(16), dim3(256), 0, stream>>>(hp, cp, (float*)d_out);
}